// Round 2
// baseline (510.587 us; speedup 1.0000x reference)
//
#include <hip/hip_runtime.h>
#include <math.h>

#define LL 2
#define BB 32
#define SS 2048
#define HH 512
#define DD 1024      // 2*H
#define W4S 2048     // attn_w row stride = 4*H

// fused scores kernel tiling
#define BM 128
#define BN 512       // full H in one block -> complete score rows locally
#define BK 32
#define NT (DD / BK)     // 32 k-tiles

typedef __attribute__((ext_vector_type(8))) short bf16x8;
typedef __attribute__((ext_vector_type(4))) float f32x4;

// fp32 pair -> packed bf16x2, round-to-nearest-even (one-time pack)
__device__ inline unsigned pk2_rne(float a, float b) {
    unsigned ua = __float_as_uint(a), ub = __float_as_uint(b);
    unsigned ra = (ua + 0x7fffu + ((ua >> 16) & 1u)) >> 16;
    unsigned rb = (ub + 0x7fffu + ((ub >> 16) & 1u)) & 0xffff0000u;
    return ra | rb;
}

// fp32 pair -> packed bf16x2, round-half-up: 2 adds + v_perm
__device__ inline unsigned pk2_hu(float a, float b) {
    unsigned ua = __float_as_uint(a) + 0x8000u;
    unsigned ub = __float_as_uint(b) + 0x8000u;
    return __builtin_amdgcn_perm(ub, ua, 0x07060302u);
}

__device__ inline float fast_tanh(float x) {
    x = fminf(9.f, fmaxf(-9.f, x));
    float e = __expf(2.f * x);
    return 1.f - 2.f * __builtin_amdgcn_rcpf(e + 1.f);
}

// async global->LDS, 16 B per lane; LDS dest = base + lane*16
__device__ inline void gl_lds16(const unsigned short* g, short* l) {
    __builtin_amdgcn_global_load_lds(
        (const __attribute__((address_space(1))) unsigned int*)g,
        (__attribute__((address_space(3))) unsigned int*)l, 16, 0, 0);
}

#define SB() __builtin_amdgcn_sched_barrier(0)

// ---------------- one-time pack: w_e fp32 -> bf16 row-major [HH][DD] ---------
// also zeros the per-batch softmax denominators
__global__ __launch_bounds__(256) void k_pack(const float* __restrict__ attn_w,
                                              unsigned short* __restrict__ Bp,
                                              float* __restrict__ den) {
    int h = blockIdx.x, t = threadIdx.x;
    if (h == 0 && t < BB) den[t] = 0.f;
    float4 v = *(const float4*)(attn_w + (size_t)h * W4S + DD + t * 4);
    uint2 r = make_uint2(pk2_rne(v.x, v.y), pk2_rne(v.z, v.w));
    *(uint2*)(Bp + (size_t)h * DD + t * 4) = r;
}

// ---------------- base[b,h] = dot(hidden[-1,b,:], w_h[h,:]) + bias[h] --------
__global__ __launch_bounds__(256) void k_base(const float* __restrict__ hidden,
                                              const float* __restrict__ attn_w,
                                              const float* __restrict__ attn_b,
                                              float* __restrict__ base) {
    int wid  = (blockIdx.x * 256 + threadIdx.x) >> 6;
    int lane = threadIdx.x & 63;
    int b = wid >> 9;
    int h = wid & (HH - 1);
    const float4* h4 = (const float4*)(hidden + (size_t)(LL - 1) * BB * DD + (size_t)b * DD);
    const float4* w4 = (const float4*)(attn_w + (size_t)h * W4S);
    float s = 0.f;
    #pragma unroll
    for (int i = 0; i < 4; i++) {
        float4 a = h4[lane + i * 64], w = w4[lane + i * 64];
        s += a.x * w.x + a.y * w.y + a.z * w.z + a.w * w.w;
    }
    #pragma unroll
    for (int off = 32; off; off >>= 1) s += __shfl_xor(s, off);
    if (lane == 0) base[b * HH + h] = s + attn_b[h];
}

// ---------------- fused GEMM + tanh + exp + context partial ------------------
// Phase-split K-loop with counted vmcnt (T3+T4) and setprio (T5):
//   BK=32, 4-slot LDS ring for B, depth-2 global_load_lds prefetch,
//   A fp32->reg->bf16 pack (no A LDS), 2 phases x 16 MFMA per K-tile.
#define LOAD_A(KT) { _Pragma("unroll") for (int mi = 0; mi < 4; mi++) { \
    pa[mi][0] = *(const float4*)(Ar + (size_t)mi * 16 * DD + (KT) * BK); \
    pa[mi][1] = *(const float4*)(Ar + (size_t)mi * 16 * DD + (KT) * BK + 4); } }

#define PACK_A() { _Pragma("unroll") for (int mi = 0; mi < 4; mi++) { \
    uint4 u; u.x = pk2_hu(pa[mi][0].x, pa[mi][0].y); u.y = pk2_hu(pa[mi][0].z, pa[mi][0].w); \
             u.z = pk2_hu(pa[mi][1].x, pa[mi][1].y); u.w = pk2_hu(pa[mi][1].z, pa[mi][1].w); \
    af[mi] = *(bf16x8*)&u; } }

#define PHASE_CORE(NH, ...) { \
    __VA_ARGS__ \
    bf16x8 b0 = *(const bf16x8*)&Bb[rb + ((NH) * 4 + 0) * 16 * BK]; \
    bf16x8 b1 = *(const bf16x8*)&Bb[rb + ((NH) * 4 + 1) * 16 * BK]; \
    bf16x8 b2 = *(const bf16x8*)&Bb[rb + ((NH) * 4 + 2) * 16 * BK]; \
    bf16x8 b3 = *(const bf16x8*)&Bb[rb + ((NH) * 4 + 3) * 16 * BK]; \
    SB(); __builtin_amdgcn_s_barrier(); SB(); \
    __builtin_amdgcn_s_setprio(1); \
    _Pragma("unroll") for (int mi = 0; mi < 4; mi++) { \
        acc[mi][(NH) * 4 + 0] = __builtin_amdgcn_mfma_f32_16x16x32_bf16(af[mi], b0, acc[mi][(NH) * 4 + 0], 0, 0, 0); \
        acc[mi][(NH) * 4 + 1] = __builtin_amdgcn_mfma_f32_16x16x32_bf16(af[mi], b1, acc[mi][(NH) * 4 + 1], 0, 0, 0); \
        acc[mi][(NH) * 4 + 2] = __builtin_amdgcn_mfma_f32_16x16x32_bf16(af[mi], b2, acc[mi][(NH) * 4 + 2], 0, 0, 0); \
        acc[mi][(NH) * 4 + 3] = __builtin_amdgcn_mfma_f32_16x16x32_bf16(af[mi], b3, acc[mi][(NH) * 4 + 3], 0, 0, 0); \
    } \
    __builtin_amdgcn_s_setprio(0); SB(); }

#define ENDB() { __builtin_amdgcn_s_barrier(); SB(); }

__global__ __launch_bounds__(512, 2) void k_scores(const float* __restrict__ enc,
                                                   const unsigned short* __restrict__ Bp,
                                                   const float* __restrict__ base,
                                                   const float* __restrict__ vw,
                                                   float* __restrict__ den,
                                                   float* __restrict__ part,
                                                   float* __restrict__ attn_out) {
    __shared__ short Bs[4][BN * BK];    // 4 x 32 KB ring, granule-XOR swizzled

    const int tid  = threadIdx.x;
    const int wid  = tid >> 6;
    const int lane = tid & 63;
    const int lm   = lane & 15;
    const int kq   = lane >> 4;
    const int wr   = wid >> 2;                 // 0..1  (m-slice of 64)
    const int wc   = wid & 3;                  // 0..3  (n-slice of 128)
    const int m0   = blockIdx.x * BM;
    const int b    = m0 >> 11;
    const int srow = m0 & (SS - 1);
    const int wn   = wid * 64;                 // B-staging slice (8 waves x 64 rows)

    // A direct-to-reg: lane lm covers row wr*64+mi*16+lm, k-chunk kq*8
    const float* Ar = enc + (size_t)(m0 + wr * 64 + lm) * DD + kq * 8;

    // B staging via global_load_lds: wave covers rows wn..wn+63, 4 instrs of 16 rows.
    // LDS granule (row, g) holds global granule g ^ ((row>>1)&3)  (bank-spread).
    const int brow = lane >> 2;                          // 0..15 within 16-row group
    const int bgsw = (lane & 3) ^ ((lane >> 3) & 3);     // swizzled source granule
    const unsigned short* Bg = Bp + (size_t)(wn + brow) * DD + bgsw * 8;

    // B read base: row wc*128 + (..)*16 + lm, granule kq ^ ((lm>>1)&3)
    const int rb = (wc * 128 + lm) * BK + (kq ^ ((lm >> 1) & 3)) * 8;

    f32x4 acc[4][8];
    #pragma unroll
    for (int i = 0; i < 4; i++)
        #pragma unroll
        for (int j = 0; j < 8; j++) acc[i][j] = (f32x4){0.f, 0.f, 0.f, 0.f};

    float4 pa[4][2];
    bf16x8 af[4];

    // ---- prologue: A(0) regs, B(0)+B(1) gl_lds; wait B(0)+A(0), keep B(1) ----
    LOAD_A(0);
    #pragma unroll
    for (int i = 0; i < 4; i++)
        gl_lds16(Bg + (size_t)(i * 16) * DD, &Bs[0][(wn + i * 16) * BK]);
    #pragma unroll
    for (int i = 0; i < 4; i++)
        gl_lds16(Bg + (size_t)(i * 16) * DD + BK, &Bs[1][(wn + i * 16) * BK]);
    asm volatile("s_waitcnt vmcnt(4)" ::: "memory");
    SB();
    __builtin_amdgcn_s_barrier();
    SB();

    for (int kt = 0; kt < NT; kt++) {
        const short* Bb = Bs[kt & 3];
        short* Bn = Bs[(kt + 2) & 3];
        PACK_A();                       // compiler emits counted vmcnt for pa here
        PHASE_CORE(0,
            if (kt + 1 < NT) { LOAD_A(kt + 1); }
            if (kt + 2 < NT) {
                gl_lds16(Bg + (size_t)0 * DD + (kt + 2) * BK, &Bn[(wn + 0) * BK]);
                gl_lds16(Bg + (size_t)16 * DD + (kt + 2) * BK, &Bn[(wn + 16) * BK]);
            } )
        ENDB();
        PHASE_CORE(1,
            if (kt + 2 < NT) {
                gl_lds16(Bg + (size_t)32 * DD + (kt + 2) * BK, &Bn[(wn + 32) * BK]);
                gl_lds16(Bg + (size_t)48 * DD + (kt + 2) * BK, &Bn[(wn + 48) * BK]);
            } )
        // tile-end: per-wave counted wait BEFORE barrier -> collective after it.
        // steady: keep A(kt+1) x8 + B(kt+2) x4 in flight, require B(kt+1) done.
        if (kt + 2 < NT)      { asm volatile("s_waitcnt vmcnt(12)" ::: "memory"); }
        else if (kt + 1 < NT) { asm volatile("s_waitcnt vmcnt(8)"  ::: "memory"); }
        else                  { asm volatile("s_waitcnt vmcnt(0)"  ::: "memory"); }
        SB();
        ENDB();
    }

    // ---- epilogue: scores -> exp -> den atomic -> context partial ----
    __syncthreads();                     // full drain; reuse Bs as reduction space
    float* red  = (float*)&Bs[0][0];     // [4][128]
    float* esh  = red + 4 * BM;          // [128]
    float* dsum = esh + BM;              // [2]

    const float* basep = base + b * HH + wc * 128;
    const float* vp    = vw + wc * 128;
    float p[4][4] = {};
    #pragma unroll
    for (int ni = 0; ni < 8; ni++) {
        int nl = ni * 16 + lm;
        float bs = basep[nl];
        float vv = vp[nl];
        #pragma unroll
        for (int mi = 0; mi < 4; mi++)
            #pragma unroll
            for (int r = 0; r < 4; r++)
                p[mi][r] += vv * fast_tanh(acc[mi][ni][r] + bs);
    }
    #pragma unroll
    for (int off = 8; off; off >>= 1)
        #pragma unroll
        for (int mi = 0; mi < 4; mi++)
            #pragma unroll
            for (int r = 0; r < 4; r++)
                p[mi][r] += __shfl_xor(p[mi][r], off);
    if (lm == 0) {
        #pragma unroll
        for (int mi = 0; mi < 4; mi++)
            #pragma unroll
            for (int r = 0; r < 4; r++)
                red[wc * BM + wr * 64 + mi * 16 + kq * 4 + r] = p[mi][r];
    }
    __syncthreads();
    if (tid < BM) {
        float s = red[tid] + red[BM + tid] + red[2 * BM + tid] + red[3 * BM + tid];
        s = fminf(s, 80.f);              // safety: exp stays finite
        float e = __expf(s);
        attn_out[b * SS + srow + tid] = e;   // unnormalized; k_finish scales
        esh[tid] = e;
        float rs = e;
        #pragma unroll
        for (int off = 32; off; off >>= 1) rs += __shfl_xor(rs, off);
        if ((tid & 63) == 0) dsum[tid >> 6] = rs;
    }
    __syncthreads();
    if (tid == 0) atomicAdd(den + b, dsum[0] + dsum[1]);

    // context partial: part[2*bx+half][d] = sum_{m in half} e_m * enc[m][d]
    const int half = tid >> 8;           // 0..1 -> rows half*64..+63
    const int c4   = tid & 255;          // float4 column
    const float4* e4 = (const float4*)(enc + (size_t)(m0 + half * 64) * DD) + c4;
    float4 a = {0.f, 0.f, 0.f, 0.f};
    #pragma unroll 8
    for (int j = 0; j < 64; j++) {
        float w = esh[half * 64 + j];
        float4 ev = e4[(size_t)j * (DD / 4)];
        a.x += w * ev.x; a.y += w * ev.y;
        a.z += w * ev.z; a.w += w * ev.w;
    }
    *(float4*)(part + (size_t)(blockIdx.x * 2 + half) * DD + c4 * 4) = a;
}

// ---------------- finish: ctx reduce + weight normalize ----------------------
__global__ __launch_bounds__(256) void k_finish(const float* __restrict__ part,
                                                const float* __restrict__ den,
                                                float* __restrict__ ctx,
                                                float* __restrict__ attn) {
    int b = blockIdx.x, y = blockIdx.y, t = threadIdx.x;
    float inv = 1.f / den[b];
    if (y < 4) {
        int d = y * 256 + t;
        float s = 0.f;
        #pragma unroll
        for (int j = 0; j < 32; j++) s += part[(size_t)(b * 32 + j) * DD + d];
        ctx[b * DD + d] = s * inv;
    } else {
        int sid = (y - 4) * 256 + t;
        attn[b * SS + sid] *= inv;
    }
}

extern "C" void kernel_launch(void* const* d_in, const int* in_sizes, int n_in,
                              void* d_out, int out_size, void* d_ws, size_t ws_size,
                              hipStream_t stream) {
    const float* hidden = (const float*)d_in[0];   // (L,B,D)
    const float* enc    = (const float*)d_in[1];   // (B,S,D)
    const float* attn_w = (const float*)d_in[2];   // (H,4H)
    const float* attn_b = (const float*)d_in[3];   // (H,)
    const float* v_w    = (const float*)d_in[4];   // (1,H)

    float* out      = (float*)d_out;
    float* ctx_out  = out;               // (B,1,D)
    float* attn_out = out + BB * DD;     // (B,1,S)

    float* base = (float*)d_ws;                                // B*H
    float* den  = base + BB * HH;                              // 32 (+pad)
    unsigned short* Bp = (unsigned short*)(den + 64);          // H*D bf16 (1 MB)
    float* part = (float*)(Bp + (size_t)HH * DD);              // 1024*D (4 MB)

    hipLaunchKernelGGL(k_pack, dim3(HH), dim3(256), 0, stream, attn_w, Bp, den);
    hipLaunchKernelGGL(k_base, dim3(BB * HH / 4), dim3(256), 0, stream,
                       hidden, attn_w, attn_b, base);
    hipLaunchKernelGGL(k_scores, dim3(BB * SS / BM), dim3(512), 0, stream,
                       enc, Bp, base, v_w, den, part, attn_out);
    hipLaunchKernelGGL(k_finish, dim3(BB, 12), dim3(256), 0, stream,
                       part, den, ctx_out, attn_out);
}